// Round 4
// baseline (83.163 us; speedup 1.0000x reference)
//
#include <hip/hip_runtime.h>

constexpr int D = 64;  // D_FEAT == UNITS == 64

// ---------------------------------------------------------------------------
// Kernel A (edge-centric, x4 vectorized): offs[n] = lower_bound(ids, n).
// Thread t handles edges 4t..4t+3.
// ---------------------------------------------------------------------------
__global__ void seg_bounds(const int* __restrict__ ids, int* __restrict__ offs,
                           int n_nodes, int n_edges) {
    const int t  = blockIdx.x * blockDim.x + threadIdx.x;
    const int e0 = t * 4;
    if (e0 >= n_edges) return;
    const int4 c4   = *(const int4*)(ids + e0);           // ids[e0..e0+3]
    const int  prev = (e0 == 0) ? -1 : ids[e0 - 1];
    const int  cur[4] = {c4.x, c4.y, c4.z, c4.w};
    int p = prev;
#pragma unroll
    for (int u = 0; u < 4; ++u) {
        const int e = e0 + u;
        for (int n = p + 1; n <= cur[u]; ++n) offs[n] = e;
        p = cur[u];
    }
    if (e0 + 4 >= n_edges) {  // last thread: close out trailing empty nodes
        for (int n = p + 1; n <= n_nodes; ++n) offs[n] = n_edges;
    }
}

// ---------------------------------------------------------------------------
// Kernel B: one wave per node. Block = 256 = 4 waves = 4 nodes.
// - Edge loop: predicated 4-row batches, unroll x8 -> deg<=32 (93% of nodes,
//   Poisson(25)) streams in ONE issue burst (8 KB in flight/wave).
// - Dense phase: W read directly from global (16 KB, L1-resident) -> no sW
//   staging, no block barrier, DS port nearly idle. LDS = 1 KB (sx only).
// ---------------------------------------------------------------------------
template <bool USE_OFFS>
__global__ __launch_bounds__(256, 6) void gcn_fused(
    const float* __restrict__ src,   // [N, 64]
    const float* __restrict__ dst,   // [E, 64]
    const int*   __restrict__ ids,   // [E] sorted (fallback path only)
    const int*   __restrict__ offs,  // [N+1] segment offsets
    const float* __restrict__ Wm,    // [64, 64]
    const float* __restrict__ bv,    // [64]
    float*       __restrict__ out,   // [N, 64]
    int n_nodes, int n_edges)
{
    __shared__ float sx[4][D];   // 1 KB: one x-row per wave

    const int tid  = threadIdx.x;
    const int wave = tid >> 6;
    const int lane = tid & 63;
    const int node = blockIdx.x * 4 + wave;
    if (node >= n_nodes) return;  // never taken (50000 % 4 == 0)

    int start_, end_;
    if (USE_OFFS) {
        start_ = offs[node];       // wave-uniform -> scalar broadcast loads
        end_   = offs[node + 1];
    } else {
        const int key = node + (lane >> 5);
        int lo = 0, hi = n_edges;
        while (lo < hi) {
            const int mid = (lo + hi) >> 1;
            if (ids[mid] < key) lo = mid + 1; else hi = mid;
        }
        start_ = __shfl(lo, 0);
        end_   = __shfl(lo, 32);
    }
    const int cnt = end_ - start_;

    const int g = lane >> 4;   // 4 groups of 16 lanes; group g -> row start+4b+g
    const int f = lane & 15;   // float4 chunk within a 256B row

    // Prefetch src row EARLY so its HBM latency hides under edge streaming.
    float4 s4 = make_float4(0.f, 0.f, 0.f, 0.f);
    if (lane < 16) s4 = *((const float4*)(src + (size_t)node * D) + f);

    const float4* dst4 = (const float4*)dst;
    float4 a = make_float4(0.f, 0.f, 0.f, 0.f);

    const int nb   = (cnt + 3) >> 2;   // 4-row batches needed (0 if cnt==0)
    const int nb8  = (nb + 7) & ~7;    // round to x8: no remainder loop
    const int last = end_ - 1;         // clamp target (only used when cnt>0)

#pragma unroll 1
    for (int b = 0; b < nb8; b += 8) {
#pragma unroll
        for (int u = 0; u < 8; ++u) {
            const int r  = start_ + g + 4 * (b + u);
            const int rc = min(r, last);             // stay in-segment (L1-hot)
            const float4 v = dst4[rc * (D / 4) + f]; // rc*16+f < 20M: int ok
            const bool  m = (r < end_);
            a.x += m ? v.x : 0.0f;
            a.y += m ? v.y : 0.0f;
            a.z += m ? v.z : 0.0f;
            a.w += m ? v.w : 0.0f;
        }
    }

    // Reduce the 4 groups -> lanes 0..15 get full feature sums.
    a.x += __shfl_xor(a.x, 16); a.y += __shfl_xor(a.y, 16);
    a.z += __shfl_xor(a.z, 16); a.w += __shfl_xor(a.w, 16);
    a.x += __shfl_xor(a.x, 32); a.y += __shfl_xor(a.y, 32);
    a.z += __shfl_xor(a.z, 32); a.w += __shfl_xor(a.w, 32);

    // x = mean + src -> LDS (lanes 0..15, float4 each).
    if (lane < 16) {
        const float inv = 1.0f / fmaxf((float)cnt, 1.0f);
        float4 xv;
        xv.x = fmaf(a.x, inv, s4.x);
        xv.y = fmaf(a.y, inv, s4.y);
        xv.z = fmaf(a.z, inv, s4.z);
        xv.w = fmaf(a.w, inv, s4.w);
        *((float4*)&sx[wave][0] + f) = xv;
    }
    // same-wave LDS RAW: compiler inserts lgkmcnt wait; each wave only
    // touches sx[wave] -> no barrier needed.

    // out[node][lane] = b[lane] + sum_k x[k] * W[k][lane]
    // W row k is 256B; lane reads W[k*64+lane]: coalesced, L1-resident (16KB).
    float acc = bv[lane];
#pragma unroll 4
    for (int k = 0; k < D; k += 4) {
        const float4 xk = *(const float4*)&sx[wave][k];  // LDS broadcast
        acc = fmaf(xk.x, Wm[(k + 0) * D + lane], acc);
        acc = fmaf(xk.y, Wm[(k + 1) * D + lane], acc);
        acc = fmaf(xk.z, Wm[(k + 2) * D + lane], acc);
        acc = fmaf(xk.w, Wm[(k + 3) * D + lane], acc);
    }
    out[(size_t)node * D + lane] = acc;
}

extern "C" void kernel_launch(void* const* d_in, const int* in_sizes, int n_in,
                              void* d_out, int out_size, void* d_ws, size_t ws_size,
                              hipStream_t stream) {
    const float* src = (const float*)d_in[0];
    // d_in[1] = edge (unused by reference)
    const float* dst = (const float*)d_in[2];
    const int*   ids = (const int*)d_in[3];
    const float* Wm  = (const float*)d_in[4];
    const float* bv  = (const float*)d_in[5];
    float* out = (float*)d_out;

    const int n_nodes = in_sizes[0] / D;   // 50000
    const int n_edges = in_sizes[3];       // 1250000

    const int nblocks = (n_nodes + 3) / 4; // 12500

    if (ws_size >= (size_t)(n_nodes + 1) * sizeof(int)) {
        int* offs = (int*)d_ws;
        const int t4 = (n_edges + 3) / 4;
        seg_bounds<<<(t4 + 255) / 256, 256, 0, stream>>>(ids, offs, n_nodes, n_edges);
        gcn_fused<true><<<nblocks, 256, 0, stream>>>(src, dst, ids, offs, Wm, bv, out,
                                                     n_nodes, n_edges);
    } else {
        gcn_fused<false><<<nblocks, 256, 0, stream>>>(src, dst, ids, nullptr, Wm, bv, out,
                                                      n_nodes, n_edges);
    }
}

// Round 5
// 73.239 us; speedup vs baseline: 1.1355x; 1.1355x over previous
//
#include <hip/hip_runtime.h>

constexpr int D = 64;  // D_FEAT == UNITS == 64

// ---------------------------------------------------------------------------
// Kernel A (edge-centric, x4 vectorized): offs[n] = lower_bound(ids, n).
// ---------------------------------------------------------------------------
__global__ void seg_bounds(const int* __restrict__ ids, int* __restrict__ offs,
                           int n_nodes, int n_edges) {
    const int t  = blockIdx.x * blockDim.x + threadIdx.x;
    const int e0 = t * 4;
    if (e0 >= n_edges) return;
    const int4 c4   = *(const int4*)(ids + e0);
    const int  prev = (e0 == 0) ? -1 : ids[e0 - 1];
    const int  cur[4] = {c4.x, c4.y, c4.z, c4.w};
    int p = prev;
#pragma unroll
    for (int u = 0; u < 4; ++u) {
        const int e = e0 + u;
        for (int n = p + 1; n <= cur[u]; ++n) offs[n] = e;
        p = cur[u];
    }
    if (e0 + 4 >= n_edges) {
        for (int n = p + 1; n <= n_nodes; ++n) offs[n] = n_edges;
    }
}

// ---------------------------------------------------------------------------
// Kernel B: TWO nodes per wave (segments adjacent -> one contiguous stream).
// Block = 256 = 4 waves = 8 nodes. R3 structure otherwise: sW staged in LDS
// (DS port, not vmem), predicated unroll-4 streaming, occupancy 8 blocks/CU.
// ---------------------------------------------------------------------------
template <bool USE_OFFS>
__global__ __launch_bounds__(256, 8) void gcn_fused(
    const float* __restrict__ src,   // [N, 64]
    const float* __restrict__ dst,   // [E, 64]
    const int*   __restrict__ ids,   // [E] sorted (fallback path only)
    const int*   __restrict__ offs,  // [N+1] segment offsets
    const float* __restrict__ Wm,    // [64, 64]
    const float* __restrict__ bv,    // [64]
    float*       __restrict__ out,   // [N, 64]
    int n_nodes, int n_edges)
{
    __shared__ float sW[D][D];   // 16 KB
    __shared__ float sx[8][D];   // 2 KB: two x-rows per wave

    const int tid = threadIdx.x;

    // Stage W via float4: coalesced, conflict-free. (R4 lesson: keep W on the
    // DS port — reading it from global adds 64 vmem instrs/wave, +24us issue.)
    {
        const float4* W4  = (const float4*)Wm;
        float4*       sW4 = (float4*)&sW[0][0];
#pragma unroll
        for (int i = 0; i < 4; ++i) sW4[tid + 256 * i] = W4[tid + 256 * i];
    }
    __syncthreads();  // only barrier; before any divergent exit

    const int wave = tid >> 6;
    const int lane = tid & 63;
    const int n0   = (blockIdx.x * 4 + wave) * 2;  // even node
    if (n0 >= n_nodes) return;  // never taken (50000 % 8 == 0)

    int s0, s1, s2;
    if (USE_OFFS) {
        const int2 o01 = *(const int2*)(offs + n0);  // n0 even -> 8B aligned
        s0 = o01.x; s1 = o01.y;
        s2 = offs[n0 + 2];
    } else {
        // fallback: two binary searches (keys n0 / n0+1 in half-waves, then n0+2)
        int key = n0 + (lane >> 5);
        int lo = 0, hi = n_edges;
        while (lo < hi) { const int mid = (lo + hi) >> 1; if (ids[mid] < key) lo = mid + 1; else hi = mid; }
        s0 = __shfl(lo, 0); s1 = __shfl(lo, 32);
        int lo2 = 0, hi2 = n_edges; const int key2 = n0 + 2;
        while (lo2 < hi2) { const int mid = (lo2 + hi2) >> 1; if (ids[mid] < key2) lo2 = mid + 1; else hi2 = mid; }
        s2 = lo2;
    }

    const int g = lane >> 4;   // 4 groups; group g reads row s0+4b+g
    const int f = lane & 15;   // float4 chunk within a 256B row
    const int h = g & 1;       // for lanes<32: which node this lane finalizes

    // Prefetch BOTH src rows early (contiguous 512B, lanes 0..31, 1 instr).
    float4 s4 = make_float4(0.f, 0.f, 0.f, 0.f);
    if (lane < 32) s4 = *((const float4*)src + (size_t)n0 * (D / 4) + lane);

    const float4* dst4 = (const float4*)dst;
    float4 a0 = make_float4(0.f, 0.f, 0.f, 0.f);
    float4 a1 = make_float4(0.f, 0.f, 0.f, 0.f);

    const int total = s2 - s0;
    const int nb    = (total + 3) >> 2;   // 4-row batches
    const int nb4   = (nb + 3) & ~3;      // round to x4: no remainder loop
    const int last  = s2 - 1;             // clamp (valid iff total>0)

#pragma unroll 1
    for (int b = 0; b < nb4; b += 4) {
#pragma unroll
        for (int u = 0; u < 4; ++u) {
            const int r  = s0 + g + 4 * (b + u);
            const int rc = min(r, last);             // in-stream clamp (L1-hot)
            const float4 v = dst4[rc * (D / 4) + f]; // rc*16+f < 20M: int ok
            const bool m0 = (r < s1);
            const bool m1 = (r >= s1) & (r < s2);
            a0.x += m0 ? v.x : 0.0f;  a1.x += m1 ? v.x : 0.0f;
            a0.y += m0 ? v.y : 0.0f;  a1.y += m1 ? v.y : 0.0f;
            a0.z += m0 ? v.z : 0.0f;  a1.z += m1 ? v.z : 0.0f;
            a0.w += m0 ? v.w : 0.0f;  a1.w += m1 ? v.w : 0.0f;
        }
    }

    // Reduce 4 groups for both accumulators -> all lanes hold full sums.
    a0.x += __shfl_xor(a0.x, 16); a0.y += __shfl_xor(a0.y, 16);
    a0.z += __shfl_xor(a0.z, 16); a0.w += __shfl_xor(a0.w, 16);
    a1.x += __shfl_xor(a1.x, 16); a1.y += __shfl_xor(a1.y, 16);
    a1.z += __shfl_xor(a1.z, 16); a1.w += __shfl_xor(a1.w, 16);
    a0.x += __shfl_xor(a0.x, 32); a0.y += __shfl_xor(a0.y, 32);
    a0.z += __shfl_xor(a0.z, 32); a0.w += __shfl_xor(a0.w, 32);
    a1.x += __shfl_xor(a1.x, 32); a1.y += __shfl_xor(a1.y, 32);
    a1.z += __shfl_xor(a1.z, 32); a1.w += __shfl_xor(a1.w, 32);

    // x = mean + src for both rows: lanes 0..15 -> node0, 16..31 -> node1.
    // One contiguous 512B LDS write (sx[wave*2+h][4f..4f+3]).
    if (lane < 32) {
        const int   cnt = h ? (s2 - s1) : (s1 - s0);
        const float inv = 1.0f / fmaxf((float)cnt, 1.0f);
        const float4 av = h ? a1 : a0;
        float4 xv;
        xv.x = fmaf(av.x, inv, s4.x);
        xv.y = fmaf(av.y, inv, s4.y);
        xv.z = fmaf(av.z, inv, s4.z);
        xv.w = fmaf(av.w, inv, s4.w);
        *((float4*)&sx[wave * 2][0] + lane) = xv;
    }
    // same-wave LDS RAW: compiler inserts lgkmcnt wait; each wave only
    // touches sx[wave*2..wave*2+1] -> no barrier needed.

    // out[n][lane] = b[lane] + sum_k x[k]*W[k][lane]; each W read feeds BOTH nodes.
    const float bvl = bv[lane];
    float acc_a = bvl, acc_b = bvl;
#pragma unroll
    for (int k = 0; k < D; k += 4) {
        const float4 x0 = *(const float4*)&sx[wave * 2][k];      // broadcast
        const float4 x1 = *(const float4*)&sx[wave * 2 + 1][k];  // broadcast
#pragma unroll
        for (int j = 0; j < 4; ++j) {
            const float w = sW[k + j][lane];                     // stride-1
            const float xj0 = (&x0.x)[j];
            const float xj1 = (&x1.x)[j];
            acc_a = fmaf(xj0, w, acc_a);
            acc_b = fmaf(xj1, w, acc_b);
        }
    }
    out[(size_t)n0 * D + lane]       = acc_a;
    out[(size_t)(n0 + 1) * D + lane] = acc_b;
}

extern "C" void kernel_launch(void* const* d_in, const int* in_sizes, int n_in,
                              void* d_out, int out_size, void* d_ws, size_t ws_size,
                              hipStream_t stream) {
    const float* src = (const float*)d_in[0];
    // d_in[1] = edge (unused by reference)
    const float* dst = (const float*)d_in[2];
    const int*   ids = (const int*)d_in[3];
    const float* Wm  = (const float*)d_in[4];
    const float* bv  = (const float*)d_in[5];
    float* out = (float*)d_out;

    const int n_nodes = in_sizes[0] / D;   // 50000
    const int n_edges = in_sizes[3];       // 1250000

    const int nblocks = (n_nodes + 7) / 8; // 6250 (8 nodes per block)

    if (ws_size >= (size_t)(n_nodes + 1) * sizeof(int)) {
        int* offs = (int*)d_ws;
        const int t4 = (n_edges + 3) / 4;
        seg_bounds<<<(t4 + 255) / 256, 256, 0, stream>>>(ids, offs, n_nodes, n_edges);
        gcn_fused<true><<<nblocks, 256, 0, stream>>>(src, dst, ids, offs, Wm, bv, out,
                                                     n_nodes, n_edges);
    } else {
        gcn_fused<false><<<nblocks, 256, 0, stream>>>(src, dst, ids, nullptr, Wm, bv, out,
                                                      n_nodes, n_edges);
    }
}

// Round 7
// 59.415 us; speedup vs baseline: 1.3997x; 1.2327x over previous
//
#include <hip/hip_runtime.h>

constexpr int D = 64;  // D_FEAT == UNITS == 64

typedef float nfloat4 __attribute__((ext_vector_type(4)));  // builtin-compatible

// ---------------------------------------------------------------------------
// Kernel A (edge-centric, x4 vectorized): offs[n] = lower_bound(ids, n).
// ---------------------------------------------------------------------------
__global__ void seg_bounds(const int* __restrict__ ids, int* __restrict__ offs,
                           int n_nodes, int n_edges) {
    const int t  = blockIdx.x * blockDim.x + threadIdx.x;
    const int e0 = t * 4;
    if (e0 >= n_edges) return;
    const int4 c4   = *(const int4*)(ids + e0);
    const int  prev = (e0 == 0) ? -1 : ids[e0 - 1];
    const int  cur[4] = {c4.x, c4.y, c4.z, c4.w};
    int p = prev;
#pragma unroll
    for (int u = 0; u < 4; ++u) {
        const int e = e0 + u;
        for (int n = p + 1; n <= cur[u]; ++n) offs[n] = e;
        p = cur[u];
    }
    if (e0 + 4 >= n_edges) {
        for (int n = p + 1; n <= n_nodes; ++n) offs[n] = n_edges;
    }
}

// ---------------------------------------------------------------------------
// Kernel B: TWO nodes per wave; quad-uniform branch streaming.
// Per 16-row quad the node-membership condition is wave-uniform (s_cbranch):
//   interior quads: unpredicated v_add, no clamp, nontemporal load
//   boundary quads: fmaf-by-{0,1} weights (cheaper than cndmask+add pairs)
// Accumulation value & order per lane unchanged vs R3/R5 -> absmax identical.
// ---------------------------------------------------------------------------
template <bool USE_OFFS>
__global__ __launch_bounds__(256, 8) void gcn_fused(
    const float* __restrict__ src,   // [N, 64]
    const float* __restrict__ dst,   // [E, 64]
    const int*   __restrict__ ids,   // [E] sorted (fallback path only)
    const int*   __restrict__ offs,  // [N+1] segment offsets
    const float* __restrict__ Wm,    // [64, 64]
    const float* __restrict__ bv,    // [64]
    float*       __restrict__ out,   // [N, 64]
    int n_nodes, int n_edges)
{
    __shared__ float sW[D][D];   // 16 KB (DS port, not vmem — R4 lesson)
    __shared__ float sx[8][D];   // 2 KB

    const int tid = threadIdx.x;
    {
        const float4* W4  = (const float4*)Wm;
        float4*       sW4 = (float4*)&sW[0][0];
#pragma unroll
        for (int i = 0; i < 4; ++i) sW4[tid + 256 * i] = W4[tid + 256 * i];
    }
    __syncthreads();  // only barrier; before any divergent exit

    const int wave = tid >> 6;
    const int lane = tid & 63;
    const int n0   = (blockIdx.x * 4 + wave) * 2;  // even node
    if (n0 >= n_nodes) return;  // never taken (50000 % 8 == 0)

    int s0, s1, s2;
    if (USE_OFFS) {
        const int2 o01 = *(const int2*)(offs + n0);  // n0 even -> 8B aligned
        s0 = o01.x; s1 = o01.y;
        s2 = offs[n0 + 2];
    } else {
        int key = n0 + (lane >> 5);
        int lo = 0, hi = n_edges;
        while (lo < hi) { const int mid = (lo + hi) >> 1; if (ids[mid] < key) lo = mid + 1; else hi = mid; }
        s0 = __shfl(lo, 0); s1 = __shfl(lo, 32);
        int lo2 = 0, hi2 = n_edges; const int key2 = n0 + 2;
        while (lo2 < hi2) { const int mid = (lo2 + hi2) >> 1; if (ids[mid] < key2) lo2 = mid + 1; else hi2 = mid; }
        s2 = lo2;
    }

    const int g = lane >> 4;   // group g reads row q0 + 4u + g
    const int f = lane & 15;   // float4 chunk within a 256B row
    const int h = g & 1;

    // Prefetch BOTH src rows early (contiguous 512B, lanes 0..31).
    float4 s4 = make_float4(0.f, 0.f, 0.f, 0.f);
    if (lane < 32) s4 = *((const float4*)src + (size_t)n0 * (D / 4) + lane);

    const nfloat4* dst4 = (const nfloat4*)dst;
    float4 a0 = make_float4(0.f, 0.f, 0.f, 0.f);
    float4 a1 = make_float4(0.f, 0.f, 0.f, 0.f);

    const int total = s2 - s0;
    const int nb    = (total + 3) >> 2;   // 4-row batches
    const int nb4   = (nb + 3) & ~3;      // round to quad of batches
    const int last  = s2 - 1;             // clamp (valid iff total>0)

#pragma unroll 1
    for (int b = 0; b < nb4; b += 4) {
        const int q0   = s0 + 4 * b;      // first row of this 16-row quad
        const int qend = q0 + 16;         // one past last row
        if (qend <= s1) {
            // ---- interior node0: all rows valid & belong to a0 ----
#pragma unroll
            for (int u = 0; u < 4; ++u) {
                const int r = q0 + 4 * u + g;
                const nfloat4 v = __builtin_nontemporal_load(&dst4[r * (D / 4) + f]);
                a0.x += v.x; a0.y += v.y; a0.z += v.z; a0.w += v.w;
            }
        } else if (q0 >= s1 && qend <= s2) {
            // ---- interior node1 ----
#pragma unroll
            for (int u = 0; u < 4; ++u) {
                const int r = q0 + 4 * u + g;
                const nfloat4 v = __builtin_nontemporal_load(&dst4[r * (D / 4) + f]);
                a1.x += v.x; a1.y += v.y; a1.z += v.z; a1.w += v.w;
            }
        } else {
            // ---- boundary / tail quad: weight-by-{0,1} fmaf ----
#pragma unroll
            for (int u = 0; u < 4; ++u) {
                const int r  = q0 + 4 * u + g;
                const int rc = min(r, last);             // clamp: L1-hot real row
                const nfloat4 v = dst4[rc * (D / 4) + f];
                const float w0 = (r < s1) ? 1.0f : 0.0f;
                const float w1 = ((r >= s1) & (r < s2)) ? 1.0f : 0.0f;
                a0.x = fmaf(w0, v.x, a0.x);  a1.x = fmaf(w1, v.x, a1.x);
                a0.y = fmaf(w0, v.y, a0.y);  a1.y = fmaf(w1, v.y, a1.y);
                a0.z = fmaf(w0, v.z, a0.z);  a1.z = fmaf(w1, v.z, a1.z);
                a0.w = fmaf(w0, v.w, a0.w);  a1.w = fmaf(w1, v.w, a1.w);
            }
        }
    }

    // Reduce 4 groups for both accumulators.
    a0.x += __shfl_xor(a0.x, 16); a0.y += __shfl_xor(a0.y, 16);
    a0.z += __shfl_xor(a0.z, 16); a0.w += __shfl_xor(a0.w, 16);
    a1.x += __shfl_xor(a1.x, 16); a1.y += __shfl_xor(a1.y, 16);
    a1.z += __shfl_xor(a1.z, 16); a1.w += __shfl_xor(a1.w, 16);
    a0.x += __shfl_xor(a0.x, 32); a0.y += __shfl_xor(a0.y, 32);
    a0.z += __shfl_xor(a0.z, 32); a0.w += __shfl_xor(a0.w, 32);
    a1.x += __shfl_xor(a1.x, 32); a1.y += __shfl_xor(a1.y, 32);
    a1.z += __shfl_xor(a1.z, 32); a1.w += __shfl_xor(a1.w, 32);

    // x = mean + src: lanes 0..15 -> node0, 16..31 -> node1 (512B LDS write).
    if (lane < 32) {
        const int   cnt = h ? (s2 - s1) : (s1 - s0);
        const float inv = 1.0f / fmaxf((float)cnt, 1.0f);
        const float4 av = h ? a1 : a0;
        float4 xv;
        xv.x = fmaf(av.x, inv, s4.x);
        xv.y = fmaf(av.y, inv, s4.y);
        xv.z = fmaf(av.z, inv, s4.z);
        xv.w = fmaf(av.w, inv, s4.w);
        *((float4*)&sx[wave * 2][0] + lane) = xv;
    }
    // same-wave LDS RAW: compiler inserts lgkmcnt wait; no barrier needed.

    // out[n][lane] = b[lane] + sum_k x[k]*W[k][lane]; W read feeds both nodes.
    const float bvl = bv[lane];
    float acc_a = bvl, acc_b = bvl;
#pragma unroll
    for (int k = 0; k < D; k += 4) {
        const float4 x0 = *(const float4*)&sx[wave * 2][k];      // broadcast
        const float4 x1 = *(const float4*)&sx[wave * 2 + 1][k];  // broadcast
#pragma unroll
        for (int j = 0; j < 4; ++j) {
            const float w = sW[k + j][lane];                     // stride-1
            acc_a = fmaf((&x0.x)[j], w, acc_a);
            acc_b = fmaf((&x1.x)[j], w, acc_b);
        }
    }
    __builtin_nontemporal_store(acc_a, &out[(size_t)n0 * D + lane]);
    __builtin_nontemporal_store(acc_b, &out[(size_t)(n0 + 1) * D + lane]);
}

extern "C" void kernel_launch(void* const* d_in, const int* in_sizes, int n_in,
                              void* d_out, int out_size, void* d_ws, size_t ws_size,
                              hipStream_t stream) {
    const float* src = (const float*)d_in[0];
    // d_in[1] = edge (unused by reference)
    const float* dst = (const float*)d_in[2];
    const int*   ids = (const int*)d_in[3];
    const float* Wm  = (const float*)d_in[4];
    const float* bv  = (const float*)d_in[5];
    float* out = (float*)d_out;

    const int n_nodes = in_sizes[0] / D;   // 50000
    const int n_edges = in_sizes[3];       // 1250000

    const int nblocks = (n_nodes + 7) / 8; // 6250 (8 nodes per block)

    if (ws_size >= (size_t)(n_nodes + 1) * sizeof(int)) {
        int* offs = (int*)d_ws;
        const int t4 = (n_edges + 3) / 4;
        seg_bounds<<<(t4 + 255) / 256, 256, 0, stream>>>(ids, offs, n_nodes, n_edges);
        gcn_fused<true><<<nblocks, 256, 0, stream>>>(src, dst, ids, offs, Wm, bv, out,
                                                     n_nodes, n_edges);
    } else {
        gcn_fused<false><<<nblocks, 256, 0, stream>>>(src, dst, ids, nullptr, Wm, bv, out,
                                                      n_nodes, n_edges);
    }
}